// Round 1
// baseline (1798.317 us; speedup 1.0000x reference)
//
#include <hip/hip_runtime.h>

// ---- problem constants ----
#define T_TOK 8192
#define HDIM  2048
#define NEXP  8
#define RLORA 16
#define AUX_COEF 0.01f
#define Z_COEF   0.001f
// SCALING = lora_alpha/r = 32/16 = 2
#define SCALE_LORA 2.0f

// ---- GEMM tiling ----
#define TILE 128
#define BK   64
#define NTILES 16                 // 2048/128
#define MAX_TILES 136             // max sum of per-expert padded M-tiles
#define ROWS_CAP (MAX_TILES*TILE) // 17408

typedef __attribute__((ext_vector_type(4))) float f4;
typedef __attribute__((ext_vector_type(8))) short s8;
typedef __attribute__((ext_vector_type(4))) unsigned short us4;

__device__ __forceinline__ unsigned short f2b(float f) {
    union { float f; unsigned int u; } c; c.f = f;
    unsigned int u = c.u;
    unsigned int r = (u + 0x7fffu + ((u >> 16) & 1u)) >> 16;  // RNE
    return (unsigned short)r;
}
__device__ __forceinline__ float b2f(unsigned short b) {
    union { unsigned int u; float f; } c; c.u = ((unsigned int)b) << 16;
    return c.f;
}

// async global->LDS, 16B per lane. LDS dst must be wave-uniform base; HW adds lane*16.
__device__ __forceinline__ void async_ld16(const unsigned short* g, const unsigned short* l) {
    __builtin_amdgcn_global_load_lds(
        (const __attribute__((address_space(1))) unsigned int*)(unsigned long long)g,
        (__attribute__((address_space(3))) unsigned int*)(unsigned int)(unsigned long long)l,
        16, 0, 0);
}

// ---------------- init: zero counters + idx_list (ws is poisoned 0xAA each call) ----
__global__ void init_k(int* counts, int* cursors, float* imp, float* zsum, int* idx_list) {
    int i = blockIdx.x * 256 + threadIdx.x;
    if (i < NEXP) { counts[i] = 0; cursors[i] = 0; imp[i] = 0.f; }
    if (i == 0) zsum[0] = 0.f;
    if (i < ROWS_CAP) idx_list[i] = 0;
}

// ---------------- router: logits, top-2, loss partials -----------------------------
__global__ __launch_bounds__(256) void router_k(const float* __restrict__ x,
                                                const float* __restrict__ wg,
                                                int* counts, float* imp, float* zsum,
                                                int* top_e, float* top_g) {
    int wave = threadIdx.x >> 6, lane = threadIdx.x & 63;
    int t = blockIdx.x * 4 + wave;
    float acc[NEXP];
#pragma unroll
    for (int e = 0; e < NEXP; e++) acc[e] = 0.f;
    const float* xr = x + (size_t)t * HDIM;
    for (int k0 = 0; k0 < HDIM; k0 += 256) {
        f4 xv = *(const f4*)(xr + k0 + lane * 4);
#pragma unroll
        for (int e = 0; e < NEXP; e++) {
            f4 wv = *(const f4*)(wg + e * HDIM + k0 + lane * 4);
            acc[e] += xv.x * wv.x + xv.y * wv.y + xv.z * wv.z + xv.w * wv.w;
        }
    }
#pragma unroll
    for (int e = 0; e < NEXP; e++)
        for (int off = 32; off; off >>= 1) acc[e] += __shfl_xor(acc[e], off, 64);
    if (lane == 0) {
        int e0 = 0; float v0 = acc[0];
        for (int e = 1; e < NEXP; e++) if (acc[e] > v0) { v0 = acc[e]; e0 = e; }
        int e1 = -1; float v1 = -1e30f;
        for (int e = 0; e < NEXP; e++) if (e != e0 && acc[e] > v1) { v1 = acc[e]; e1 = e; }
        float ex1 = __expf(v1 - v0);
        float g0 = 1.f / (1.f + ex1), g1 = ex1 / (1.f + ex1);
        top_e[2 * t] = e0; top_e[2 * t + 1] = e1;
        top_g[2 * t] = g0; top_g[2 * t + 1] = g1;
        atomicAdd(&counts[e0], 1); atomicAdd(&counts[e1], 1);
        atomicAdd(&imp[e0], g0);   atomicAdd(&imp[e1], g1);
        float s = 0.f;
        for (int e = 0; e < NEXP; e++) s += __expf(acc[e] - v0);
        float lse = v0 + __logf(s);
        atomicAdd(zsum, lse * lse);
    }
}

// ---------------- scan: padded tile offsets + routing loss --------------------------
__global__ void scan_k(const int* counts, const float* imp, const float* zsum,
                       int* tile_off, int* row_off, int* total_tiles, float* loss_out) {
    if (threadIdx.x == 0 && blockIdx.x == 0) {
        int to = 0;
        float lb = 0.f;
        for (int e = 0; e < NEXP; e++) {
            tile_off[e] = to;
            row_off[e] = to * TILE;
            to += (counts[e] + TILE - 1) / TILE;
            lb += imp[e] * (float)counts[e];
        }
        tile_off[NEXP] = to;
        total_tiles[0] = to;
        float T2 = (float)T_TOK * (float)T_TOK;
        loss_out[0] = AUX_COEF * ((float)NEXP * lb / T2) + Z_COEF * (zsum[0] / (float)T_TOK);
    }
}

// ---------------- assign: compact per-expert slot lists -----------------------------
__global__ void assign_k(const int* top_e, int* cursors, const int* row_off,
                         int* idx_list, int* slotmap) {
    int t = blockIdx.x * 256 + threadIdx.x;
    if (t >= T_TOK) return;
    for (int k = 0; k < 2; k++) {
        int e = top_e[2 * t + k];
        int pos = atomicAdd(&cursors[e], 1);
        int slot = row_off[e] + pos;
        idx_list[slot] = t;
        slotmap[2 * t + k] = slot;
    }
}

// ---------------- cast fp32 x -> bf16 ----------------------------------------------
__global__ __launch_bounds__(256) void cast_k(const float* __restrict__ x,
                                              unsigned short* __restrict__ xb) {
    size_t gid = (size_t)blockIdx.x * 256 + threadIdx.x;
    f4 v = *(const f4*)(x + gid * 4);
    us4 o = { f2b(v.x), f2b(v.y), f2b(v.z), f2b(v.w) };
    *(us4*)(xb + gid * 4) = o;
}

// ---------------- fold: W_eff = W + 2*(B@A), cast to bf16 ---------------------------
// w: [E][2048][2048], A: [E][16][2048], B: [E][2048][16] -> out bf16 [E][2048][2048]
__global__ __launch_bounds__(256) void fold_k(const float* __restrict__ w,
                                              const float* __restrict__ A,
                                              const float* __restrict__ B,
                                              unsigned short* __restrict__ out) {
    size_t gid = (size_t)blockIdx.x * 256 + threadIdx.x;
    int h4 = (int)(gid & 511);
    int o  = (int)((gid >> 9) & 2047);
    int e  = (int)(gid >> 20);
    int h = h4 * 4;
    const float* Ae = A + (size_t)e * RLORA * HDIM;
    const float* Be = B + ((size_t)e * HDIM + o) * RLORA;
    const float* we = w + (((size_t)e * HDIM + o) * HDIM) + h;
    f4 acc = {0.f, 0.f, 0.f, 0.f};
#pragma unroll
    for (int r = 0; r < RLORA; r++) {
        float bv = Be[r];
        f4 av = *(const f4*)(Ae + r * HDIM + h);
        acc += bv * av;
    }
    f4 wv = *(const f4*)we;
    f4 res = wv + SCALE_LORA * acc;
    us4 ov = { f2b(res.x), f2b(res.y), f2b(res.z), f2b(res.w) };
    *(us4*)(out + gid * 4) = ov;
}

// ---------------- grouped GEMM: C[m,n] = sum_k A[m,k] * W[n,k] ----------------------
// A rows gathered via idx_list (gather=1) or direct (gather=0).
// fuse=1: epilogue a = silu(g)*u  (g read from gin at same offset), write bf16.
__global__ __launch_bounds__(256) void gemm_k(const unsigned short* __restrict__ Abase,
                                              const unsigned short* __restrict__ Wb,
                                              unsigned short* Cout,
                                              const unsigned short* gin,
                                              const int* __restrict__ idx_list,
                                              const int* __restrict__ tile_off,
                                              const int* __restrict__ total_tiles,
                                              int gather, int fuse) {
    int tl = blockIdx.x >> 4;
    if (tl >= total_tiles[0]) return;
    int nt = blockIdx.x & 15;
    int e = 0;
    while (e < NEXP - 1 && tile_off[e + 1] <= tl) e++;
    int row0 = tl * TILE;                       // global slot-row base (padded layout)
    const unsigned short* We = Wb + ((size_t)e << 22);

    int tid = threadIdx.x, lane = tid & 63, wave = tid >> 6;
    int wm = wave >> 1, wn = wave & 1;

    __shared__ unsigned short sA[TILE * BK];
    __shared__ unsigned short sB[TILE * BK];

    int srow = lane >> 3;            // 0..7
    int kseg = (lane & 7) * 8;       // element offset within BK row
    const unsigned short* aptr[4];
    const unsigned short* bptr[4];
    const unsigned short* ldsA[4];
    const unsigned short* ldsB[4];
#pragma unroll
    for (int i = 0; i < 4; i++) {
        int r = i * 32 + wave * 8 + srow;
        int arow = row0 + r;
        int atok = gather ? idx_list[arow] : arow;
        aptr[i] = Abase + (size_t)atok * HDIM + kseg;
        bptr[i] = We + (size_t)(nt * TILE + r) * HDIM + kseg;
        ldsA[i] = sA + (i * 32 + wave * 8) * BK;
        ldsB[i] = sB + (i * 32 + wave * 8) * BK;
    }

    f4 acc[4][4];
#pragma unroll
    for (int i = 0; i < 4; i++)
#pragma unroll
        for (int j = 0; j < 4; j++) acc[i][j] = (f4){0.f, 0.f, 0.f, 0.f};

    for (int k0 = 0; k0 < HDIM; k0 += BK) {
#pragma unroll
        for (int i = 0; i < 4; i++) async_ld16(aptr[i] + k0, ldsA[i]);
#pragma unroll
        for (int i = 0; i < 4; i++) async_ld16(bptr[i] + k0, ldsB[i]);
        __syncthreads();
        int rA = lane & 15;
#pragma unroll
        for (int kk = 0; kk < BK; kk += 32) {
            int kq = kk + (lane >> 4) * 8;
            s8 af[4], bf[4];
#pragma unroll
            for (int i = 0; i < 4; i++)
                af[i] = *(const s8*)(sA + (wm * 64 + i * 16 + rA) * BK + kq);
#pragma unroll
            for (int j = 0; j < 4; j++)
                bf[j] = *(const s8*)(sB + (wn * 64 + j * 16 + rA) * BK + kq);
#pragma unroll
            for (int i = 0; i < 4; i++)
#pragma unroll
                for (int j = 0; j < 4; j++)
                    acc[i][j] = __builtin_amdgcn_mfma_f32_16x16x32_bf16(af[i], bf[j], acc[i][j], 0, 0, 0);
        }
        __syncthreads();
    }

    // epilogue: C/D layout col=lane&15, row=(lane>>4)*4+reg
    int quad = lane >> 4, cl = lane & 15;
#pragma unroll
    for (int i = 0; i < 4; i++)
#pragma unroll
        for (int j = 0; j < 4; j++)
#pragma unroll
            for (int r = 0; r < 4; r++) {
                int row = row0 + wm * 64 + i * 16 + quad * 4 + r;
                int col = nt * TILE + wn * 64 + j * 16 + cl;
                size_t off = (size_t)row * HDIM + col;
                float v = acc[i][j][r];
                if (fuse) {
                    float g = b2f(gin[off]);
                    float sg = g / (1.f + __expf(-g));   // silu(g)
                    v = sg * v;
                }
                Cout[off] = f2b(v);
            }
}

// ---------------- combine: out = hidden + alpha*(g0*y[s0] + g1*y[s1]); -------------
__global__ __launch_bounds__(256) void combine_k(const float* __restrict__ hidden,
                                                 const unsigned short* __restrict__ ybuf,
                                                 const int* __restrict__ slotmap,
                                                 const float* __restrict__ top_g,
                                                 const float* __restrict__ alpha,
                                                 float* __restrict__ out) {
    size_t gid = (size_t)blockIdx.x * 256 + threadIdx.x;
    int t = (int)(gid >> 9);
    int c = ((int)gid & 511) * 4;
    int s0 = slotmap[2 * t], s1 = slotmap[2 * t + 1];
    float g0 = top_g[2 * t], g1 = top_g[2 * t + 1];
    float a = alpha[0];
    f4 hv = *(const f4*)(hidden + ((size_t)t << 11) + c);
    us4 y0 = *(const us4*)(ybuf + ((size_t)s0 << 11) + c);
    us4 y1 = *(const us4*)(ybuf + ((size_t)s1 << 11) + c);
    f4 r;
    r.x = hv.x + a * (g0 * b2f(y0.x) + g1 * b2f(y1.x));
    r.y = hv.y + a * (g0 * b2f(y0.y) + g1 * b2f(y1.y));
    r.z = hv.z + a * (g0 * b2f(y0.z) + g1 * b2f(y1.z));
    r.w = hv.w + a * (g0 * b2f(y0.w) + g1 * b2f(y1.w));
    *(f4*)(out + ((size_t)t << 11) + c) = r;
}

extern "C" void kernel_launch(void* const* d_in, const int* in_sizes, int n_in,
                              void* d_out, int out_size, void* d_ws, size_t ws_size,
                              hipStream_t stream) {
    const float* x      = (const float*)d_in[0];
    const float* w_gate = (const float*)d_in[1];
    const float* gate_w = (const float*)d_in[2];
    const float* gate_A = (const float*)d_in[3];
    const float* gate_B = (const float*)d_in[4];
    const float* up_w   = (const float*)d_in[5];
    const float* up_A   = (const float*)d_in[6];
    const float* up_B   = (const float*)d_in[7];
    const float* down_w = (const float*)d_in[8];
    const float* down_A = (const float*)d_in[9];
    const float* down_B = (const float*)d_in[10];
    const float* alpha  = (const float*)d_in[11];
    float* out = (float*)d_out;

    // ---- workspace carve-up (256B aligned) ----
    char* ws = (char*)d_ws;
    size_t off = 0;
    auto carve = [&](size_t bytes) -> void* {
        void* p = ws + off;
        off = (off + bytes + 255) & ~(size_t)255;
        return p;
    };
    int*   counts   = (int*)carve(NEXP * 4);
    int*   cursors  = (int*)carve(NEXP * 4);
    float* imp      = (float*)carve(NEXP * 4);
    float* zsum     = (float*)carve(4);
    int*   tile_off = (int*)carve((NEXP + 1) * 4);
    int*   row_off  = (int*)carve(NEXP * 4);
    int*   total_t  = (int*)carve(4);
    int*   top_e    = (int*)carve(2 * T_TOK * 4);
    float* top_g    = (float*)carve(2 * T_TOK * 4);
    int*   slotmap  = (int*)carve(2 * T_TOK * 4);
    int*   idx_list = (int*)carve(ROWS_CAP * 4);
    unsigned short* Xbf  = (unsigned short*)carve((size_t)T_TOK * HDIM * 2);
    unsigned short* Wbuf = (unsigned short*)carve((size_t)NEXP * HDIM * HDIM * 2);
    unsigned short* gbuf = (unsigned short*)carve((size_t)ROWS_CAP * HDIM * 2);
    unsigned short* ybuf = (unsigned short*)carve((size_t)ROWS_CAP * HDIM * 2);

    dim3 blk(256);

    init_k<<<dim3(ROWS_CAP / 256), blk, 0, stream>>>(counts, cursors, imp, zsum, idx_list);
    router_k<<<dim3(T_TOK / 4), blk, 0, stream>>>(x, w_gate, counts, imp, zsum, top_e, top_g);
    scan_k<<<dim3(1), dim3(64), 0, stream>>>(counts, imp, zsum, tile_off, row_off, total_t,
                                             out + (size_t)T_TOK * HDIM);
    assign_k<<<dim3(T_TOK / 256), blk, 0, stream>>>(top_e, cursors, row_off, idx_list, slotmap);
    cast_k<<<dim3((size_t)T_TOK * HDIM / 4 / 256), blk, 0, stream>>>(x, Xbf);

    const int gemm_grid = MAX_TILES * NTILES;

    // gate: g = Xe @ Wg_eff.T
    fold_k<<<dim3(32768), blk, 0, stream>>>(gate_w, gate_A, gate_B, Wbuf);
    gemm_k<<<dim3(gemm_grid), blk, 0, stream>>>(Xbf, Wbuf, gbuf, gbuf, idx_list, tile_off,
                                                total_t, 1, 0);
    // up + fused act: a = silu(g) * u  (overwrites gbuf)
    fold_k<<<dim3(32768), blk, 0, stream>>>(up_w, up_A, up_B, Wbuf);
    gemm_k<<<dim3(gemm_grid), blk, 0, stream>>>(Xbf, Wbuf, gbuf, gbuf, idx_list, tile_off,
                                                total_t, 1, 1);
    // down: y = a @ Wd_eff.T
    fold_k<<<dim3(32768), blk, 0, stream>>>(down_w, down_A, down_B, Wbuf);
    gemm_k<<<dim3(gemm_grid), blk, 0, stream>>>(gbuf, Wbuf, ybuf, ybuf, idx_list, tile_off,
                                                total_t, 0, 0);

    combine_k<<<dim3((size_t)T_TOK * HDIM / 4 / 256), blk, 0, stream>>>(x, ybuf, slotmap,
                                                                        top_g, alpha, out);
}

// Round 2
// 1519.112 us; speedup vs baseline: 1.1838x; 1.1838x over previous
//
#include <hip/hip_runtime.h>

// ---- problem constants ----
#define T_TOK 8192
#define HDIM  2048
#define NEXP  8
#define RLORA 16
#define AUX_COEF 0.01f
#define Z_COEF   0.001f
// SCALING = lora_alpha/r = 32/16 = 2
#define SCALE_LORA 2.0f

// ---- GEMM tiling ----
#define TILE 128
#define BK   64
#define NTILES 16                 // 2048/128
#define MAX_TILES 136             // max sum of per-expert padded M-tiles
#define ROWS_CAP (MAX_TILES*TILE) // 17408

typedef __attribute__((ext_vector_type(4))) float f4;
typedef __attribute__((ext_vector_type(8))) short s8;
typedef __attribute__((ext_vector_type(4))) unsigned short us4;

__device__ __forceinline__ unsigned short f2b(float f) {
    union { float f; unsigned int u; } c; c.f = f;
    unsigned int u = c.u;
    unsigned int r = (u + 0x7fffu + ((u >> 16) & 1u)) >> 16;  // RNE
    return (unsigned short)r;
}
__device__ __forceinline__ float b2f(unsigned short b) {
    union { unsigned int u; float f; } c; c.u = ((unsigned int)b) << 16;
    return c.f;
}

// async global->LDS, 16B per lane. LDS dst must be wave-uniform base; HW adds lane*16.
__device__ __forceinline__ void async_ld16(const unsigned short* g, const unsigned short* l) {
    __builtin_amdgcn_global_load_lds(
        (const __attribute__((address_space(1))) unsigned int*)(unsigned long long)g,
        (__attribute__((address_space(3))) unsigned int*)(unsigned int)(unsigned long long)l,
        16, 0, 0);
}

// ---------------- init: zero counters + idx_list (ws is poisoned 0xAA each call) ----
__global__ void init_k(int* counts, int* cursors, float* imp, float* zsum, int* idx_list) {
    int i = blockIdx.x * 256 + threadIdx.x;
    if (i < NEXP) { counts[i] = 0; cursors[i] = 0; imp[i] = 0.f; }
    if (i == 0) zsum[0] = 0.f;
    if (i < ROWS_CAP) idx_list[i] = 0;
}

// ---------------- router: logits, top-2, loss partials -----------------------------
__global__ __launch_bounds__(256) void router_k(const float* __restrict__ x,
                                                const float* __restrict__ wg,
                                                int* counts, float* imp, float* zsum,
                                                int* top_e, float* top_g) {
    int wave = threadIdx.x >> 6, lane = threadIdx.x & 63;
    int t = blockIdx.x * 4 + wave;
    float acc[NEXP];
#pragma unroll
    for (int e = 0; e < NEXP; e++) acc[e] = 0.f;
    const float* xr = x + (size_t)t * HDIM;
    for (int k0 = 0; k0 < HDIM; k0 += 256) {
        f4 xv = *(const f4*)(xr + k0 + lane * 4);
#pragma unroll
        for (int e = 0; e < NEXP; e++) {
            f4 wv = *(const f4*)(wg + e * HDIM + k0 + lane * 4);
            acc[e] += xv.x * wv.x + xv.y * wv.y + xv.z * wv.z + xv.w * wv.w;
        }
    }
#pragma unroll
    for (int e = 0; e < NEXP; e++)
        for (int off = 32; off; off >>= 1) acc[e] += __shfl_xor(acc[e], off, 64);
    if (lane == 0) {
        int e0 = 0; float v0 = acc[0];
        for (int e = 1; e < NEXP; e++) if (acc[e] > v0) { v0 = acc[e]; e0 = e; }
        int e1 = -1; float v1 = -1e30f;
        for (int e = 0; e < NEXP; e++) if (e != e0 && acc[e] > v1) { v1 = acc[e]; e1 = e; }
        float ex1 = __expf(v1 - v0);
        float g0 = 1.f / (1.f + ex1), g1 = ex1 / (1.f + ex1);
        top_e[2 * t] = e0; top_e[2 * t + 1] = e1;
        top_g[2 * t] = g0; top_g[2 * t + 1] = g1;
        atomicAdd(&counts[e0], 1); atomicAdd(&counts[e1], 1);
        atomicAdd(&imp[e0], g0);   atomicAdd(&imp[e1], g1);
        float s = 0.f;
        for (int e = 0; e < NEXP; e++) s += __expf(acc[e] - v0);
        float lse = v0 + __logf(s);
        atomicAdd(zsum, lse * lse);
    }
}

// ---------------- scan: padded tile offsets + routing loss --------------------------
__global__ void scan_k(const int* counts, const float* imp, const float* zsum,
                       int* tile_off, int* row_off, int* total_tiles, float* loss_out) {
    if (threadIdx.x == 0 && blockIdx.x == 0) {
        int to = 0;
        float lb = 0.f;
        for (int e = 0; e < NEXP; e++) {
            tile_off[e] = to;
            row_off[e] = to * TILE;
            to += (counts[e] + TILE - 1) / TILE;
            lb += imp[e] * (float)counts[e];
        }
        tile_off[NEXP] = to;
        total_tiles[0] = to;
        float T2 = (float)T_TOK * (float)T_TOK;
        loss_out[0] = AUX_COEF * ((float)NEXP * lb / T2) + Z_COEF * (zsum[0] / (float)T_TOK);
    }
}

// ---------------- assign: compact per-expert slot lists -----------------------------
__global__ void assign_k(const int* top_e, int* cursors, const int* row_off,
                         int* idx_list, int* slotmap) {
    int t = blockIdx.x * 256 + threadIdx.x;
    if (t >= T_TOK) return;
    for (int k = 0; k < 2; k++) {
        int e = top_e[2 * t + k];
        int pos = atomicAdd(&cursors[e], 1);
        int slot = row_off[e] + pos;
        idx_list[slot] = t;
        slotmap[2 * t + k] = slot;
    }
}

// ---------------- cast fp32 x -> bf16 ----------------------------------------------
__global__ __launch_bounds__(256) void cast_k(const float* __restrict__ x,
                                              unsigned short* __restrict__ xb) {
    size_t gid = (size_t)blockIdx.x * 256 + threadIdx.x;
    f4 v = *(const f4*)(x + gid * 4);
    us4 o = { f2b(v.x), f2b(v.y), f2b(v.z), f2b(v.w) };
    *(us4*)(xb + gid * 4) = o;
}

// ---------------- fold: W_eff = W + 2*(B@A), cast to bf16 ---------------------------
// w: [E][2048][2048], A: [E][16][2048], B: [E][2048][16] -> out bf16 [E][2048][2048]
// Each thread: 4 h-cols (f4) x 4 o-rows -> A fragment reused 4x.
__global__ __launch_bounds__(256) void fold_k(const float* __restrict__ w,
                                              const float* __restrict__ A,
                                              const float* __restrict__ B,
                                              unsigned short* __restrict__ out) {
    size_t gid = (size_t)blockIdx.x * 256 + threadIdx.x;
    int h = ((int)(gid & 511)) * 4;          // 512 h-groups
    int o = ((int)((gid >> 9) & 511)) * 4;   // 512 o-groups
    int e = (int)(gid >> 18);
    const float* Ae = A + (size_t)e * RLORA * HDIM;
    f4 av[RLORA];
#pragma unroll
    for (int r = 0; r < RLORA; r++) av[r] = *(const f4*)(Ae + r * HDIM + h);
#pragma unroll
    for (int j = 0; j < 4; j++) {
        const float* Be = B + ((size_t)e * HDIM + o + j) * RLORA;
        f4 acc = {0.f, 0.f, 0.f, 0.f};
#pragma unroll
        for (int r = 0; r < RLORA; r++) acc += Be[r] * av[r];
        size_t woff = ((size_t)e * HDIM + o + j) * HDIM + h;
        f4 wv = *(const f4*)(w + woff);
        f4 res = wv + SCALE_LORA * acc;
        us4 ov = { f2b(res.x), f2b(res.y), f2b(res.z), f2b(res.w) };
        *(us4*)(out + woff) = ov;
    }
}

// ---------------- grouped GEMM: C[m,n] = sum_k A[m,k] * W[n,k] ----------------------
// LDS layout XOR-swizzled: chunk c (16B) of row r stored at slot p = c ^ (r&7).
// Staging picks global chunk (L&7)^(L>>3) per lane so global_load_lds (base+L*16)
// lands chunks at swizzled slots. Fragment reads then hit all 32 banks (2-way max).
__global__ __launch_bounds__(256) void gemm_k(const unsigned short* __restrict__ Abase,
                                              const unsigned short* __restrict__ Wb,
                                              unsigned short* Cout,
                                              const unsigned short* gin,
                                              const int* __restrict__ idx_list,
                                              const int* __restrict__ tile_off,
                                              const int* __restrict__ total_tiles,
                                              int gather, int fuse) {
    int tl = blockIdx.x >> 4;
    if (tl >= total_tiles[0]) return;
    int nt = blockIdx.x & 15;
    int e = 0;
    while (e < NEXP - 1 && tile_off[e + 1] <= tl) e++;
    int row0 = tl * TILE;                       // global slot-row base (padded layout)
    const unsigned short* We = Wb + ((size_t)e << 22);

    int tid = threadIdx.x, lane = tid & 63, wave = tid >> 6;
    int wm = wave >> 1, wn = wave & 1;

    __shared__ unsigned short sA[TILE * BK];
    __shared__ unsigned short sB[TILE * BK];

    int srow = lane >> 3;                       // 0..7 (row within 8-row wave block)
    int kseg = ((lane & 7) ^ srow) * 8;         // swizzled chunk fetch
    const unsigned short* aptr[4];
    const unsigned short* bptr[4];
    const unsigned short* ldsA[4];
    const unsigned short* ldsB[4];
#pragma unroll
    for (int i = 0; i < 4; i++) {
        int r = i * 32 + wave * 8 + srow;
        int arow = row0 + r;
        int atok = gather ? idx_list[arow] : arow;
        aptr[i] = Abase + (size_t)atok * HDIM + kseg;
        bptr[i] = We + (size_t)(nt * TILE + r) * HDIM + kseg;
        ldsA[i] = sA + (i * 32 + wave * 8) * BK;
        ldsB[i] = sB + (i * 32 + wave * 8) * BK;
    }

    f4 acc[4][4];
#pragma unroll
    for (int i = 0; i < 4; i++)
#pragma unroll
        for (int j = 0; j < 4; j++) acc[i][j] = (f4){0.f, 0.f, 0.f, 0.f};

    int rA = lane & 15;
    int quad = lane >> 4;
    for (int k0 = 0; k0 < HDIM; k0 += BK) {
#pragma unroll
        for (int i = 0; i < 4; i++) async_ld16(aptr[i] + k0, ldsA[i]);
#pragma unroll
        for (int i = 0; i < 4; i++) async_ld16(bptr[i] + k0, ldsB[i]);
        __syncthreads();
#pragma unroll
        for (int kk = 0; kk < BK; kk += 32) {
            int c0 = (kk >> 3) + quad;              // chunk index 0..7
            int p8 = ((c0 ^ (rA & 7)) << 3);        // swizzled slot, element offset
            s8 af[4], bf[4];
#pragma unroll
            for (int i = 0; i < 4; i++)
                af[i] = *(const s8*)(sA + (wm * 64 + i * 16 + rA) * BK + p8);
#pragma unroll
            for (int j = 0; j < 4; j++)
                bf[j] = *(const s8*)(sB + (wn * 64 + j * 16 + rA) * BK + p8);
#pragma unroll
            for (int i = 0; i < 4; i++)
#pragma unroll
                for (int j = 0; j < 4; j++)
                    acc[i][j] = __builtin_amdgcn_mfma_f32_16x16x32_bf16(af[i], bf[j], acc[i][j], 0, 0, 0);
        }
        __syncthreads();
    }

    // epilogue: C/D layout col=lane&15, row=(lane>>4)*4+reg
    int cl = lane & 15;
#pragma unroll
    for (int i = 0; i < 4; i++)
#pragma unroll
        for (int j = 0; j < 4; j++)
#pragma unroll
            for (int r = 0; r < 4; r++) {
                int row = row0 + wm * 64 + i * 16 + quad * 4 + r;
                int col = nt * TILE + wn * 64 + j * 16 + cl;
                size_t off = (size_t)row * HDIM + col;
                float v = acc[i][j][r];
                if (fuse) {
                    float g = b2f(gin[off]);
                    float sg = g / (1.f + __expf(-g));   // silu(g)
                    v = sg * v;
                }
                Cout[off] = f2b(v);
            }
}

// ---------------- combine: out = hidden + alpha*(g0*y[s0] + g1*y[s1]); -------------
__global__ __launch_bounds__(256) void combine_k(const float* __restrict__ hidden,
                                                 const unsigned short* __restrict__ ybuf,
                                                 const int* __restrict__ slotmap,
                                                 const float* __restrict__ top_g,
                                                 const float* __restrict__ alpha,
                                                 float* __restrict__ out) {
    size_t gid = (size_t)blockIdx.x * 256 + threadIdx.x;
    int t = (int)(gid >> 9);
    int c = ((int)gid & 511) * 4;
    int s0 = slotmap[2 * t], s1 = slotmap[2 * t + 1];
    float g0 = top_g[2 * t], g1 = top_g[2 * t + 1];
    float a = alpha[0];
    f4 hv = *(const f4*)(hidden + ((size_t)t << 11) + c);
    us4 y0 = *(const us4*)(ybuf + ((size_t)s0 << 11) + c);
    us4 y1 = *(const us4*)(ybuf + ((size_t)s1 << 11) + c);
    f4 r;
    r.x = hv.x + a * (g0 * b2f(y0.x) + g1 * b2f(y1.x));
    r.y = hv.y + a * (g0 * b2f(y0.y) + g1 * b2f(y1.y));
    r.z = hv.z + a * (g0 * b2f(y0.z) + g1 * b2f(y1.z));
    r.w = hv.w + a * (g0 * b2f(y0.w) + g1 * b2f(y1.w));
    *(f4*)(out + ((size_t)t << 11) + c) = r;
}

extern "C" void kernel_launch(void* const* d_in, const int* in_sizes, int n_in,
                              void* d_out, int out_size, void* d_ws, size_t ws_size,
                              hipStream_t stream) {
    const float* x      = (const float*)d_in[0];
    const float* w_gate = (const float*)d_in[1];
    const float* gate_w = (const float*)d_in[2];
    const float* gate_A = (const float*)d_in[3];
    const float* gate_B = (const float*)d_in[4];
    const float* up_w   = (const float*)d_in[5];
    const float* up_A   = (const float*)d_in[6];
    const float* up_B   = (const float*)d_in[7];
    const float* down_w = (const float*)d_in[8];
    const float* down_A = (const float*)d_in[9];
    const float* down_B = (const float*)d_in[10];
    const float* alpha  = (const float*)d_in[11];
    float* out = (float*)d_out;

    // ---- workspace carve-up (256B aligned) ----
    char* ws = (char*)d_ws;
    size_t off = 0;
    auto carve = [&](size_t bytes) -> void* {
        void* p = ws + off;
        off = (off + bytes + 255) & ~(size_t)255;
        return p;
    };
    int*   counts   = (int*)carve(NEXP * 4);
    int*   cursors  = (int*)carve(NEXP * 4);
    float* imp      = (float*)carve(NEXP * 4);
    float* zsum     = (float*)carve(4);
    int*   tile_off = (int*)carve((NEXP + 1) * 4);
    int*   row_off  = (int*)carve(NEXP * 4);
    int*   total_t  = (int*)carve(4);
    int*   top_e    = (int*)carve(2 * T_TOK * 4);
    float* top_g    = (float*)carve(2 * T_TOK * 4);
    int*   slotmap  = (int*)carve(2 * T_TOK * 4);
    int*   idx_list = (int*)carve(ROWS_CAP * 4);
    unsigned short* Xbf  = (unsigned short*)carve((size_t)T_TOK * HDIM * 2);
    unsigned short* Wbuf = (unsigned short*)carve((size_t)NEXP * HDIM * HDIM * 2);
    unsigned short* gbuf = (unsigned short*)carve((size_t)ROWS_CAP * HDIM * 2);
    unsigned short* ybuf = (unsigned short*)carve((size_t)ROWS_CAP * HDIM * 2);

    dim3 blk(256);

    init_k<<<dim3(ROWS_CAP / 256), blk, 0, stream>>>(counts, cursors, imp, zsum, idx_list);
    router_k<<<dim3(T_TOK / 4), blk, 0, stream>>>(x, w_gate, counts, imp, zsum, top_e, top_g);
    scan_k<<<dim3(1), dim3(64), 0, stream>>>(counts, imp, zsum, tile_off, row_off, total_t,
                                             out + (size_t)T_TOK * HDIM);
    assign_k<<<dim3(T_TOK / 256), blk, 0, stream>>>(top_e, cursors, row_off, idx_list, slotmap);
    cast_k<<<dim3((size_t)T_TOK * HDIM / 4 / 256), blk, 0, stream>>>(x, Xbf);

    const int gemm_grid = MAX_TILES * NTILES;
    const int fold_grid = (NEXP * 512 * 512) / 256;   // 8192

    // gate: g = Xe @ Wg_eff.T
    fold_k<<<dim3(fold_grid), blk, 0, stream>>>(gate_w, gate_A, gate_B, Wbuf);
    gemm_k<<<dim3(gemm_grid), blk, 0, stream>>>(Xbf, Wbuf, gbuf, gbuf, idx_list, tile_off,
                                                total_t, 1, 0);
    // up + fused act: a = silu(g) * u  (overwrites gbuf)
    fold_k<<<dim3(fold_grid), blk, 0, stream>>>(up_w, up_A, up_B, Wbuf);
    gemm_k<<<dim3(gemm_grid), blk, 0, stream>>>(Xbf, Wbuf, gbuf, gbuf, idx_list, tile_off,
                                                total_t, 1, 1);
    // down: y = a @ Wd_eff.T
    fold_k<<<dim3(fold_grid), blk, 0, stream>>>(down_w, down_A, down_B, Wbuf);
    gemm_k<<<dim3(gemm_grid), blk, 0, stream>>>(gbuf, Wbuf, ybuf, ybuf, idx_list, tile_off,
                                                total_t, 0, 0);

    combine_k<<<dim3((size_t)T_TOK * HDIM / 4 / 256), blk, 0, stream>>>(x, ybuf, slotmap,
                                                                        top_g, alpha, out);
}